// Round 10
// baseline (420.788 us; speedup 1.0000x reference)
//
#include <hip/hip_runtime.h>

// Problem constants: B=32, S=4096, H=512, E=512
typedef __attribute__((ext_vector_type(8))) short bf16x8;
typedef __attribute__((ext_vector_type(16))) float f32x16;

typedef __attribute__((address_space(3))) unsigned int lds_u32;
typedef __attribute__((address_space(1))) unsigned int glb_u32;

union frag_u { bf16x8 v; unsigned int u[4]; };

__device__ inline unsigned int cvt_pk_bf16(float lo, float hi){
  unsigned int r;
  asm("v_cvt_pk_bf16_f32 %0, %1, %2" : "=v"(r) : "v"(lo), "v"(hi));
  return r;
}
__device__ inline bf16x8 pack8(float4 a, float4 b){
  union { unsigned int u[4]; bf16x8 v; } r;
  r.u[0]=cvt_pk_bf16(a.x,a.y); r.u[1]=cvt_pk_bf16(a.z,a.w);
  r.u[2]=cvt_pk_bf16(b.x,b.y); r.u[3]=cvt_pk_bf16(b.z,b.w);
  return r.v;
}
__device__ inline float fast_tanh(float x){
  float e = __builtin_amdgcn_exp2f(x * 2.8853900817779268f);
  return 1.0f - 2.0f * __builtin_amdgcn_rcpf(e + 1.0f);
}
#define PIN8(F) asm volatile("" : "+v"((F).u[0]), "+v"((F).u[1]), \
                                  "+v"((F).u[2]), "+v"((F).u[3]))
#define LOG2E 1.4426950408889634f

// ---- K0: We [512][512] f32 -> bf16 fragment images for mfma_32x32x16.
// Record (nc,t,lane), 16B: col = nc*32+(lane&31), k = t*16+(lane>>5)*8+j.
__global__ __launch_bounds__(256) void we_conv(const float* __restrict__ We,
                                               uint4* __restrict__ weFrag){
  int gid = blockIdx.x * 256 + threadIdx.x;   // 32768 = 16 nc x 32 t x 64 lanes
  int l  = gid & 63;
  int nc = gid >> 11;
  int t  = (gid >> 6) & 31;
  int colv = nc*32 + (l & 31);
  int k = t*16 + (l >> 5)*8;
  const float4* src = (const float4*)(We + colv*512 + k);
  float4 f0 = src[0], f1 = src[1];
  weFrag[gid] = make_uint4(cvt_pk_bf16(f0.x,f0.y), cvt_pk_bf16(f0.z,f0.w),
                           cvt_pk_bf16(f1.x,f1.y), cvt_pk_bf16(f1.z,f1.w));
}

// ---- K1: gd[b][k] = h[b,:]·Wd[k,:] + bd[k] + be[k]
__global__ __launch_bounds__(256) void gd_kernel(const float* __restrict__ hvec,
                                                 const float* __restrict__ Wd,
                                                 const float* __restrict__ bd,
                                                 const float* __restrict__ be,
                                                 float* __restrict__ gd){
  __shared__ float hs[512];
  int b = blockIdx.x >> 2, kc = blockIdx.x & 3;
  int tid = threadIdx.x;
  hs[tid]       = hvec[b*512 + tid];
  hs[tid + 256] = hvec[b*512 + 256 + tid];
  __syncthreads();
  int k  = kc*128 + (tid >> 1);
  int hh = (tid & 1) * 256;
  const float4* wrow = (const float4*)(Wd + (size_t)k*512 + hh);
  const float4* hv4  = (const float4*)(hs + hh);
  float acc = 0.f;
  #pragma unroll 8
  for (int i = 0; i < 64; ++i){
    float4 w = wrow[i]; float4 u = hv4[i];
    acc += w.x*u.x + w.y*u.y + w.z*u.z + w.w*u.w;
  }
  acc += __shfl_xor(acc, 1);
  if ((tid & 1) == 0) gd[b*512 + k] = acc + bd[k] + be[k];
}

// ---- K2: fused scores + flash-style partial context.
// 8 waves x 32 rows = 256 rows/block, 512 blocks (= 2/CU x 256 CU, ONE
// generation, 4 waves/SIMD). B staged in 2x32KB LDS buffers, each chunk in
// two 16KB tranches with COUNTED vmcnt(2) waits (never 0 until tail) so
// every tranche gets >=half a phase of MFMA latency cover.
__global__ __launch_bounds__(512, 4) void score_kernel(
    const float* __restrict__ ctx, const uint4* __restrict__ weFrag,
    const float* __restrict__ gd, const float* __restrict__ Wv,
    float* __restrict__ scores, float* __restrict__ ctp,
    float* __restrict__ MS){
  __shared__ char ldsB[2*32768];             // B double buffer
  __shared__ float gdwv[1024];               // [512 gd][512 Wv]
  __shared__ float sc_lds[256];
  __shared__ float w_lds[256];
  __shared__ float red4[4];

  const int tid  = threadIdx.x;
  const int wid  = tid >> 6;                 // 0..7
  const int lane = tid & 63;
  const int bid  = blockIdx.x;               // 0..511
  const int row0 = bid * 256;
  const int b    = bid >> 4;                 // 16 blocks per batch row
  const int col  = lane & 31;
  const int hi   = lane >> 5;
  const int st   = bid & 15;                 // staggered start chunk

  // stage tranche TR (16KB, t = TR*16..TR*16+15) of chunk NC into buffer BUF
  #define ISSUE_H(NC, BUF, TR) do { \
    int _t = (TR)*16 + wid*2; \
    const char* _g = (const char*)weFrag + (size_t)(NC)*32768 + _t*1024 + lane*16; \
    char* _l = ldsB + (BUF)*32768 + _t*1024; \
    __builtin_amdgcn_global_load_lds((const glb_u32*)_g, (lds_u32*)_l, 16, 0, 0); \
    __builtin_amdgcn_global_load_lds((const glb_u32*)(_g + 1024), \
                                     (lds_u32*)(_l + 1024), 16, 0, 0); \
  } while(0)

  // 4 MFMA-group pipeline for half H (t = H*16 .. H*16+15) of current buffer
  #define HALF(H) do { \
    frag_u c0, c1, c2, c3, n0, n1, n2, n3; \
    c0.v = *(const bf16x8*)(bb + ((H)*16 +  0)*1024); \
    c1.v = *(const bf16x8*)(bb + ((H)*16 +  4)*1024); \
    c2.v = *(const bf16x8*)(bb + ((H)*16 +  8)*1024); \
    c3.v = *(const bf16x8*)(bb + ((H)*16 + 12)*1024); \
    PIN8(c0); PIN8(c1); PIN8(c2); PIN8(c3); \
    _Pragma("unroll") \
    for (int g = 0; g < 4; ++g){ \
      if (g < 3){ \
        n0.v = *(const bf16x8*)(bb + ((H)*16 + g +  1)*1024); \
        n1.v = *(const bf16x8*)(bb + ((H)*16 + g +  5)*1024); \
        n2.v = *(const bf16x8*)(bb + ((H)*16 + g +  9)*1024); \
        n3.v = *(const bf16x8*)(bb + ((H)*16 + g + 13)*1024); \
      } \
      __builtin_amdgcn_s_setprio(1); \
      accLo = __builtin_amdgcn_mfma_f32_32x32x16_bf16(afrag[(H)*16 + g     ].v, c0.v, accLo, 0, 0, 0); \
      accHi = __builtin_amdgcn_mfma_f32_32x32x16_bf16(afrag[(H)*16 + g +  4].v, c1.v, accHi, 0, 0, 0); \
      accLo = __builtin_amdgcn_mfma_f32_32x32x16_bf16(afrag[(H)*16 + g +  8].v, c2.v, accLo, 0, 0, 0); \
      accHi = __builtin_amdgcn_mfma_f32_32x32x16_bf16(afrag[(H)*16 + g + 12].v, c3.v, accHi, 0, 0, 0); \
      __builtin_amdgcn_s_setprio(0); \
      if (g < 3){ \
        PIN8(n0); PIN8(n1); PIN8(n2); PIN8(n3); \
        c0 = n0; c1 = n1; c2 = n2; c3 = n3; \
      } \
    } \
  } while(0)

  ISSUE_H(st, 0, 0);                         // chunk st, both tranches
  ISSUE_H(st, 0, 1);

  if (tid < 128)      ((float4*)gdwv)[tid] = ((const float4*)(gd + b*512))[tid];
  else if (tid < 256) ((float4*)gdwv)[tid] = ((const float4*)Wv)[tid - 128];

  // A-fragments: 32 k-steps, register/AGPR-resident, pinned.
  frag_u afrag[32];
  {
    const float4* ap = (const float4*)(ctx + (size_t)(row0 + wid*32 + col)*512 + hi*8);
    #pragma unroll
    for (int t = 0; t < 32; ++t){
      afrag[t].v = pack8(ap[t*4], ap[t*4 + 1]);
      PIN8(afrag[t]);
    }
  }

  asm volatile("s_waitcnt lgkmcnt(0)" ::: "memory");  // gdwv ds_writes done

  float sc[16];
  #pragma unroll
  for (int r = 0; r < 16; ++r) sc[r] = 0.f;

  for (int nc = 0; nc < 16; ++nc){
    const int cur = (st + nc) & 15;

    // tranche 1 of chunk nc landed (everything older drained)
    asm volatile("s_waitcnt vmcnt(2)" ::: "memory");
    __builtin_amdgcn_s_barrier();            // all waves' t1 visible; buf^1 free
    asm volatile("" ::: "memory");
    if (nc < 15) ISSUE_H((st + nc + 1) & 15, (nc + 1) & 1, 0);

    const char* bb = ldsB + (nc & 1)*32768 + lane*16;
    f32x16 accLo, accHi;
    #pragma unroll
    for (int r = 0; r < 16; ++r){ accLo[r] = 0.f; accHi[r] = 0.f; }

    HALF(0);                                 // t = 0..15

    // tranche 2 of chunk nc landed
    if (nc < 15) asm volatile("s_waitcnt vmcnt(2)" ::: "memory");
    else         asm volatile("s_waitcnt vmcnt(0)" ::: "memory");
    __builtin_amdgcn_s_barrier();            // all waves' t2 visible
    asm volatile("" ::: "memory");
    if (nc < 15) ISSUE_H((st + nc + 1) & 15, (nc + 1) & 1, 1);

    HALF(1);                                 // t = 16..31

    float gdv = gdwv[cur*32 + col];
    float wvv = gdwv[512 + cur*32 + col];
    #pragma unroll
    for (int r = 0; r < 16; ++r)
      sc[r] += fast_tanh(accLo[r] + accHi[r] + gdv) * wvv;
  }
  #undef ISSUE_H
  #undef HALF

  // reduce over the 32 output columns
  #pragma unroll
  for (int r = 0; r < 16; ++r){
    #pragma unroll
    for (int m = 1; m <= 16; m <<= 1) sc[r] += __shfl_xor(sc[r], m);
  }
  if (col == 0){
    float* so = scores + row0 + wid*32 + 4*hi;
    #pragma unroll
    for (int r = 0; r < 16; ++r){
      int rr = (r & 3) + 8*(r >> 2);
      so[rr] = sc[r];                         // global (for weights kernel)
      sc_lds[wid*32 + 4*hi + rr] = sc[r];     // block-local
    }
  }
  __syncthreads();                            // sc_lds ready; ldsB reads done

  // ---- block-local softmax partials over 256 rows
  float M = -1e30f;
  {
    const float4* s4 = (const float4*)sc_lds;
    #pragma unroll
    for (int i = 0; i < 64; ++i){
      float4 v = s4[i];
      M = fmaxf(M, fmaxf(fmaxf(v.x, v.y), fmaxf(v.z, v.w)));
    }
  }
  if (tid < 256){
    float w = __builtin_amdgcn_exp2f((sc_lds[tid] - M) * LOG2E);
    w_lds[tid] = w;
    #pragma unroll
    for (int o = 1; o < 64; o <<= 1) w += __shfl_xor(w, o);
    if ((tid & 63) == 0) red4[tid >> 6] = w;
  }
  __syncthreads();
  float S_blk = red4[0] + red4[1] + red4[2] + red4[3];

  // ---- ctp[h] = sum over 256 rows of w_r * A[r,h]; 4 passes of 64 rows
  // through ldsB (64KB). Thread owns one h column (h = tid), bf16 u16 reads.
  float ctp1 = 0.f;
  #pragma unroll
  for (int p = 0; p < 4; ++p){
    if ((wid >> 1) == p){                     // waves 2p,2p+1 dump rows p*64..
      int rl = (wid & 1)*32 + col;            // row within pass: 0..63
      char* dst = ldsB + rl*1024;
      int swz = (rl & 7) << 4;
      #pragma unroll
      for (int t = 0; t < 32; ++t)
        *(uint4*)(dst + ((t*32 + hi*16) ^ swz)) = *(uint4*)&afrag[t].u[0];
    }
    __syncthreads();
    const float* wp = w_lds + p*64;
    #pragma unroll 8
    for (int r = 0; r < 64; ++r){
      unsigned int u = *(const unsigned short*)(ldsB + r*1024 + ((tid*2) ^ ((r & 7) << 4)));
      union { unsigned int q; float f; } fv; fv.q = u << 16;
      ctp1 += wp[r] * fv.f;
    }
    __syncthreads();
  }
  ctp[(size_t)bid*512 + tid] = ctp1;
  if (tid == 0){ MS[2*bid] = M; MS[2*bid + 1] = S_blk; }
}

// ---- K3: combine 16 chunk-partials per batch -> ct[b][512], mbuf[b]={M,1/den}
__global__ __launch_bounds__(256) void combine_kernel(const float* __restrict__ ctp,
                                                      const float* __restrict__ MS,
                                                      float* __restrict__ ct,
                                                      float* __restrict__ mbuf){
  __shared__ float wsh[16];
  __shared__ float msh[2];
  int b = blockIdx.x, tid = threadIdx.x;
  if (tid < 16){
    float Mi = MS[(b*16 + tid)*2];
    float Si = MS[(b*16 + tid)*2 + 1];
    float M = Mi;
    #pragma unroll
    for (int o = 1; o < 16; o <<= 1) M = fmaxf(M, __shfl_xor(M, o));
    float w = __builtin_amdgcn_exp2f((Mi - M) * LOG2E);
    float d = w * Si;
    #pragma unroll
    for (int o = 1; o < 16; o <<= 1) d += __shfl_xor(d, o);
    wsh[tid] = w;
    if (tid == 0){ msh[0] = M; msh[1] = 1.0f / d; }
  }
  __syncthreads();
  float invd = msh[1];
  float a0 = 0.f, a1 = 0.f;
  #pragma unroll
  for (int i = 0; i < 16; ++i){
    float2 v = ((const float2*)(ctp + (size_t)(b*16 + i)*512))[tid];
    float w = wsh[i];
    a0 += w * v.x; a1 += w * v.y;
  }
  ((float2*)(ct + b*512))[tid] = make_float2(a0 * invd, a1 * invd);
  if (tid == 0){ mbuf[2*b] = msh[0]; mbuf[2*b + 1] = invd; }
}

// ---- K4: weights[b][s] = exp(score - M_b) * inv_denom
__global__ __launch_bounds__(256) void weights_kernel(const float* __restrict__ scores,
                                                      const float* __restrict__ mbuf,
                                                      float* __restrict__ weights){
  int b = blockIdx.x, tid = threadIdx.x;
  float M = mbuf[2*b], invd = mbuf[2*b + 1];
  const float4* src = (const float4*)(scores + b*4096);
  float4* dst = (float4*)(weights + b*4096);
  #pragma unroll
  for (int i = 0; i < 4; ++i){
    float4 v = src[tid + i*256];
    v.x = __builtin_amdgcn_exp2f((v.x - M) * LOG2E) * invd;
    v.y = __builtin_amdgcn_exp2f((v.y - M) * LOG2E) * invd;
    v.z = __builtin_amdgcn_exp2f((v.z - M) * LOG2E) * invd;
    v.w = __builtin_amdgcn_exp2f((v.w - M) * LOG2E) * invd;
    dst[tid + i*256] = v;
  }
}

// ---- K5: r_t = [c_t,h,x]·Wr^T + br; maxout pairs -> output [32][512]
__global__ __launch_bounds__(256) void final_kernel(
    const float* __restrict__ ct, const float* __restrict__ hvec,
    const float* __restrict__ x, const float* __restrict__ Wr,
    const float* __restrict__ br, float* __restrict__ out){
  __shared__ float xs[8][1536];
  int bt = blockIdx.x >> 4;
  int it = blockIdx.x & 15;
  int tid = threadIdx.x;
  int b0 = bt * 8;
  for (int idx = tid; idx < 8*1536; idx += 256){
    int bl = idx / 1536, j = idx % 1536;
    int b = b0 + bl;
    float v = (j < 512) ? ct[b*512 + j]
            : (j < 1024) ? hvec[b*512 + (j - 512)]
            : x[b*512 + (j - 1024)];
    xs[bl][j] = v;
  }
  __syncthreads();
  int i = it*64 + (tid & 63);
  int bl0 = (tid >> 6) * 2;
  const float4* wrow = (const float4*)(Wr + (size_t)i*1536);
  const float4* x0 = (const float4*)xs[bl0];
  const float4* x1 = (const float4*)xs[bl0 + 1];
  float a0 = 0.f, a1 = 0.f;
  #pragma unroll 4
  for (int k = 0; k < 384; ++k){
    float4 w = wrow[k];
    float4 u0 = x0[k], u1 = x1[k];
    a0 += w.x*u0.x + w.y*u0.y + w.z*u0.z + w.w*u0.w;
    a1 += w.x*u1.x + w.y*u1.y + w.z*u1.z + w.w*u1.w;
  }
  float bias = br[i];
  a0 += bias; a1 += bias;
  float n0 = __shfl_xor(a0, 1);
  float n1 = __shfl_xor(a1, 1);
  if ((tid & 1) == 0){
    out[(b0 + bl0    )*512 + (i >> 1)] = fmaxf(a0, n0);
    out[(b0 + bl0 + 1)*512 + (i >> 1)] = fmaxf(a1, n1);
  }
}

extern "C" void kernel_launch(void* const* d_in, const int* in_sizes, int n_in,
                              void* d_out, int out_size, void* d_ws, size_t ws_size,
                              hipStream_t stream){
  const float* ctx  = (const float*)d_in[0];
  const float* hvec = (const float*)d_in[1];
  const float* x    = (const float*)d_in[2];
  const float* We   = (const float*)d_in[3];
  const float* be   = (const float*)d_in[4];
  const float* Wd   = (const float*)d_in[5];
  const float* bd   = (const float*)d_in[6];
  const float* Wv   = (const float*)d_in[7];
  // d_in[8] = bv: dropped (softmax shift-invariance)
  const float* Wr   = (const float*)d_in[9];
  const float* br   = (const float*)d_in[10];

  float* out     = (float*)d_out;        // output [32][512]
  float* weights = out + 32*512;         // weights [32][4096]

  char* ws = (char*)d_ws;
  char* weFrag   = ws;                                   // 512 KiB
  float* scores  = (float*)(ws + (512 << 10));           // 512 KiB
  float* ctp     = (float*)(ws + (1024 << 10));          // 1 MiB (512x512 f32)
  float* MS      = (float*)(ws + (3 << 20));             // 4 KiB
  float* mbuf    = (float*)(ws + (3 << 20) + (16 << 10)); // 256 B
  float* ct      = (float*)(ws + (3 << 20) + (32 << 10)); // 64 KiB
  float* gd      = (float*)(ws + (3 << 20) + (96 << 10)); // 64 KiB region

  we_conv<<<128, 256, 0, stream>>>(We, (uint4*)weFrag);
  gd_kernel<<<128, 256, 0, stream>>>(hvec, Wd, bd, be, gd);
  score_kernel<<<512, 512, 0, stream>>>(ctx, (const uint4*)weFrag, gd, Wv,
                                        scores, ctp, MS);
  combine_kernel<<<32, 256, 0, stream>>>(ctp, MS, ct, mbuf);
  weights_kernel<<<32, 256, 0, stream>>>(scores, mbuf, weights);
  final_kernel<<<64, 256, 0, stream>>>(ct, hvec, x, Wr, br, out);
}

// Round 11
// 221.956 us; speedup vs baseline: 1.8958x; 1.8958x over previous
//
#include <hip/hip_runtime.h>

// Problem constants: B=32, S=4096, H=512, E=512
typedef __attribute__((ext_vector_type(8))) short bf16x8;
typedef __attribute__((ext_vector_type(16))) float f32x16;

typedef __attribute__((address_space(3))) unsigned int lds_u32;
typedef __attribute__((address_space(1))) unsigned int glb_u32;

union frag_u { bf16x8 v; unsigned int u[4]; };

__device__ inline unsigned int cvt_pk_bf16(float lo, float hi){
  unsigned int r;
  asm("v_cvt_pk_bf16_f32 %0, %1, %2" : "=v"(r) : "v"(lo), "v"(hi));
  return r;
}
__device__ inline bf16x8 pack8(float4 a, float4 b){
  union { unsigned int u[4]; bf16x8 v; } r;
  r.u[0]=cvt_pk_bf16(a.x,a.y); r.u[1]=cvt_pk_bf16(a.z,a.w);
  r.u[2]=cvt_pk_bf16(b.x,b.y); r.u[3]=cvt_pk_bf16(b.z,b.w);
  return r.v;
}
__device__ inline float fast_tanh(float x){
  float e = __builtin_amdgcn_exp2f(x * 2.8853900817779268f);
  return 1.0f - 2.0f * __builtin_amdgcn_rcpf(e + 1.0f);
}
#define PIN8(F) asm volatile("" : "+v"((F).u[0]), "+v"((F).u[1]), \
                                  "+v"((F).u[2]), "+v"((F).u[3]))
#define LOG2E 1.4426950408889634f

// ---- K0: We [512][512] f32 -> bf16 fragment images for mfma_32x32x16.
// Record (nc,t,lane), 16B: col = nc*32+(lane&31), k = t*16+(lane>>5)*8+j.
__global__ __launch_bounds__(256) void we_conv(const float* __restrict__ We,
                                               uint4* __restrict__ weFrag){
  int gid = blockIdx.x * 256 + threadIdx.x;   // 32768 = 16 nc x 32 t x 64 lanes
  int l  = gid & 63;
  int nc = gid >> 11;
  int t  = (gid >> 6) & 31;
  int colv = nc*32 + (l & 31);
  int k = t*16 + (l >> 5)*8;
  const float4* src = (const float4*)(We + colv*512 + k);
  float4 f0 = src[0], f1 = src[1];
  weFrag[gid] = make_uint4(cvt_pk_bf16(f0.x,f0.y), cvt_pk_bf16(f0.z,f0.w),
                           cvt_pk_bf16(f1.x,f1.y), cvt_pk_bf16(f1.z,f1.w));
}

// ---- K1: gd[b][k] = h[b,:]·Wd[k,:] + bd[k] + be[k]
__global__ __launch_bounds__(256) void gd_kernel(const float* __restrict__ hvec,
                                                 const float* __restrict__ Wd,
                                                 const float* __restrict__ bd,
                                                 const float* __restrict__ be,
                                                 float* __restrict__ gd){
  __shared__ float hs[512];
  int b = blockIdx.x >> 2, kc = blockIdx.x & 3;
  int tid = threadIdx.x;
  hs[tid]       = hvec[b*512 + tid];
  hs[tid + 256] = hvec[b*512 + 256 + tid];
  __syncthreads();
  int k  = kc*128 + (tid >> 1);
  int hh = (tid & 1) * 256;
  const float4* wrow = (const float4*)(Wd + (size_t)k*512 + hh);
  const float4* hv4  = (const float4*)(hs + hh);
  float acc = 0.f;
  #pragma unroll 8
  for (int i = 0; i < 64; ++i){
    float4 w = wrow[i]; float4 u = hv4[i];
    acc += w.x*u.x + w.y*u.y + w.z*u.z + w.w*u.w;
  }
  acc += __shfl_xor(acc, 1);
  if ((tid & 1) == 0) gd[b*512 + k] = acc + bd[k] + be[k];
}

// ---- K2: fused scores + flash partial context. 256 blocks x 512 threads
// (8 waves x 32 rows), ONE block per CU (LDS 137KB). Each block: two 256-row
// slabs. B staged in a 4x32KB rotation, 3 chunks in flight, counted
// vmcnt(8) waits (drain only at slab tail), ONE barrier per phase.
__global__ __launch_bounds__(512, 2) void score_kernel(
    const float* __restrict__ ctx, const uint4* __restrict__ weFrag,
    const float* __restrict__ gd, const float* __restrict__ Wv,
    float* __restrict__ scores, float* __restrict__ ctp,
    float* __restrict__ MS){
  __shared__ char ldsB[4*32768];             // B rotation (128 KB)
  __shared__ float gdwv[1024];               // [512 gd][512 Wv]
  __shared__ float sc_lds[256];
  __shared__ float w_lds[256];
  __shared__ float red4[4];

  const int tid  = threadIdx.x;
  const int wid  = tid >> 6;                 // 0..7
  const int lane = tid & 63;
  const int bid  = blockIdx.x;               // 0..255
  const int row0 = bid * 512;
  const int b    = bid >> 3;                 // 8 blocks per batch
  const int col  = lane & 31;
  const int hi   = lane >> 5;
  const int st   = bid & 15;                 // staggered start chunk

  // wave wid stages t-rows wid*4..wid*4+3 (4 KB) of chunk NC into buffer BUF
  #define ISSUE(NC, BUF) do { \
    const char* _g = (const char*)weFrag + (size_t)(NC)*32768 + (wid*4)*1024 + lane*16; \
    char* _l = ldsB + (BUF)*32768 + (wid*4)*1024; \
    _Pragma("unroll") \
    for (int _i = 0; _i < 4; ++_i) \
      __builtin_amdgcn_global_load_lds((const glb_u32*)(_g + _i*1024), \
                                       (lds_u32*)(_l + _i*1024), 16, 0, 0); \
  } while(0)

  // gd + Wv -> LDS once (keeps the k-loop free of stray VMEM)
  if (tid < 128)      ((float4*)gdwv)[tid] = ((const float4*)(gd + b*512))[tid];
  else if (tid < 256) ((float4*)gdwv)[tid] = ((const float4*)Wv)[tid - 128];

  for (int slab = 0; slab < 2; ++slab){
    const int srow = row0 + slab*256;

    // ---- A-prologue: 32 rows/wave, bf16, pinned (regular VMEM, fully
    // drained by pack8's data deps before B staging begins)
    frag_u afrag[32];
    {
      const float4* ap = (const float4*)(ctx + (size_t)(srow + wid*32 + col)*512 + hi*8);
      #pragma unroll
      for (int t = 0; t < 32; ++t){
        afrag[t].v = pack8(ap[t*4], ap[t*4 + 1]);
        PIN8(afrag[t]);
      }
    }
    asm volatile("s_waitcnt lgkmcnt(0)" ::: "memory");   // gdwv ready

    // ---- B-prologue: 3 chunks in flight
    ISSUE(st, 0);
    ISSUE((st + 1) & 15, 1);
    ISSUE((st + 2) & 15, 2);

    float sc[16];
    #pragma unroll
    for (int r = 0; r < 16; ++r) sc[r] = 0.f;

    for (int nc = 0; nc < 16; ++nc){
      const int cur = (st + nc) & 15;

      // chunk nc landed: outstanding after wait = chunks nc+1, nc+2 (8 loads)
      if (nc <= 13)      asm volatile("s_waitcnt vmcnt(8)" ::: "memory");
      else if (nc == 14) asm volatile("s_waitcnt vmcnt(4)" ::: "memory");
      else               asm volatile("s_waitcnt vmcnt(0)" ::: "memory");
      __builtin_amdgcn_s_barrier();          // all waves' chunk-nc slices visible
      if (nc < 13) ISSUE((st + nc + 3) & 15, (nc + 3) & 3);

      const char* bb = ldsB + (nc & 3)*32768 + lane*16;
      f32x16 accLo, accHi;
      #pragma unroll
      for (int r = 0; r < 16; ++r){ accLo[r] = 0.f; accHi[r] = 0.f; }

      frag_u c0, c1, c2, c3, n0, n1, n2, n3;
      c0.v = *(const bf16x8*)(bb +  0*1024);
      c1.v = *(const bf16x8*)(bb +  8*1024);
      c2.v = *(const bf16x8*)(bb + 16*1024);
      c3.v = *(const bf16x8*)(bb + 24*1024);
      PIN8(c0); PIN8(c1); PIN8(c2); PIN8(c3);

      #pragma unroll
      for (int g = 0; g < 8; ++g){
        if (g < 7){
          n0.v = *(const bf16x8*)(bb + (g + 1     )*1024);
          n1.v = *(const bf16x8*)(bb + (g + 1 +  8)*1024);
          n2.v = *(const bf16x8*)(bb + (g + 1 + 16)*1024);
          n3.v = *(const bf16x8*)(bb + (g + 1 + 24)*1024);
        }
        __builtin_amdgcn_s_setprio(1);
        accLo = __builtin_amdgcn_mfma_f32_32x32x16_bf16(afrag[g     ].v, c0.v, accLo, 0, 0, 0);
        accHi = __builtin_amdgcn_mfma_f32_32x32x16_bf16(afrag[g + 16].v, c2.v, accHi, 0, 0, 0);
        accLo = __builtin_amdgcn_mfma_f32_32x32x16_bf16(afrag[g +  8].v, c1.v, accLo, 0, 0, 0);
        accHi = __builtin_amdgcn_mfma_f32_32x32x16_bf16(afrag[g + 24].v, c3.v, accHi, 0, 0, 0);
        __builtin_amdgcn_s_setprio(0);
        if (g < 7){
          PIN8(n0); PIN8(n1); PIN8(n2); PIN8(n3);
          c0 = n0; c1 = n1; c2 = n2; c3 = n3;
        }
      }

      float gdv = gdwv[cur*32 + col];
      float wvv = gdwv[512 + cur*32 + col];
      #pragma unroll
      for (int r = 0; r < 16; ++r)
        sc[r] += fast_tanh(accLo[r] + accHi[r] + gdv) * wvv;
    }

    // ---- sc reduce over the 32 output columns
    #pragma unroll
    for (int r = 0; r < 16; ++r){
      #pragma unroll
      for (int m = 1; m <= 16; m <<= 1) sc[r] += __shfl_xor(sc[r], m);
    }
    if (col == 0){
      float* so = scores + srow + wid*32 + 4*hi;
      #pragma unroll
      for (int r = 0; r < 16; ++r){
        int rr = (r & 3) + 8*(r >> 2);
        so[rr] = sc[r];
        sc_lds[wid*32 + 4*hi + rr] = sc[r];
      }
    }
    __syncthreads();                          // sc_lds ready; ldsB reads done

    // ---- block-local softmax partials over 256 rows
    float M = -1e30f;
    {
      const float4* s4 = (const float4*)sc_lds;
      #pragma unroll
      for (int i = 0; i < 64; ++i){
        float4 v = s4[i];
        M = fmaxf(M, fmaxf(fmaxf(v.x, v.y), fmaxf(v.z, v.w)));
      }
    }
    if (tid < 256){
      float w = __builtin_amdgcn_exp2f((sc_lds[tid] - M) * LOG2E);
      w_lds[tid] = w;
      #pragma unroll
      for (int o = 1; o < 64; o <<= 1) w += __shfl_xor(w, o);
      if ((tid & 63) == 0) red4[tid >> 6] = w;
    }
    __syncthreads();
    float S_blk = red4[0] + red4[1] + red4[2] + red4[3];

    // ---- ctp[h] = sum_r w_r * A[r,h]; 4 passes of 64 rows via ldsB[0..64K)
    float ctp1 = 0.f;                         // h = tid
    #pragma unroll
    for (int p = 0; p < 4; ++p){
      if ((wid >> 1) == p){                   // waves 2p,2p+1 dump rows p*64..
        int rl = (wid & 1)*32 + col;
        char* dst = ldsB + rl*1024;
        int swz = (rl & 7) << 4;
        #pragma unroll
        for (int t = 0; t < 32; ++t)
          *(uint4*)(dst + ((t*32 + hi*16) ^ swz)) = *(uint4*)&afrag[t].u[0];
      }
      __syncthreads();
      const float* wp = w_lds + p*64;
      #pragma unroll 8
      for (int r = 0; r < 64; ++r){
        unsigned int u = *(const unsigned short*)(ldsB + r*1024 + ((tid*2) ^ ((r & 7) << 4)));
        union { unsigned int q; float f; } fv; fv.q = u << 16;
        ctp1 += wp[r] * fv.f;
      }
      __syncthreads();
    }
    const int sid = bid*2 + slab;             // slab index, 512 total
    ctp[(size_t)sid*512 + tid] = ctp1;
    if (tid == 0){ MS[2*sid] = M; MS[2*sid + 1] = S_blk; }
    __syncthreads();                          // ldsB free for next slab
  }
  #undef ISSUE
}

// ---- K3: combine 16 slab-partials per batch -> ct[b][512], mbuf[b]={M,1/den}
__global__ __launch_bounds__(256) void combine_kernel(const float* __restrict__ ctp,
                                                      const float* __restrict__ MS,
                                                      float* __restrict__ ct,
                                                      float* __restrict__ mbuf){
  __shared__ float wsh[16];
  __shared__ float msh[2];
  int b = blockIdx.x, tid = threadIdx.x;
  if (tid < 16){
    float Mi = MS[(b*16 + tid)*2];
    float Si = MS[(b*16 + tid)*2 + 1];
    float M = Mi;
    #pragma unroll
    for (int o = 1; o < 16; o <<= 1) M = fmaxf(M, __shfl_xor(M, o));
    float w = __builtin_amdgcn_exp2f((Mi - M) * LOG2E);
    float d = w * Si;
    #pragma unroll
    for (int o = 1; o < 16; o <<= 1) d += __shfl_xor(d, o);
    wsh[tid] = w;
    if (tid == 0){ msh[0] = M; msh[1] = 1.0f / d; }
  }
  __syncthreads();
  float invd = msh[1];
  float a0 = 0.f, a1 = 0.f;
  #pragma unroll
  for (int i = 0; i < 16; ++i){
    float2 v = ((const float2*)(ctp + (size_t)(b*16 + i)*512))[tid];
    float w = wsh[i];
    a0 += w * v.x; a1 += w * v.y;
  }
  ((float2*)(ct + b*512))[tid] = make_float2(a0 * invd, a1 * invd);
  if (tid == 0){ mbuf[2*b] = msh[0]; mbuf[2*b + 1] = invd; }
}

// ---- K4: weights[b][s] = exp(score - M_b) * inv_denom
__global__ __launch_bounds__(256) void weights_kernel(const float* __restrict__ scores,
                                                      const float* __restrict__ mbuf,
                                                      float* __restrict__ weights){
  int b = blockIdx.x, tid = threadIdx.x;
  float M = mbuf[2*b], invd = mbuf[2*b + 1];
  const float4* src = (const float4*)(scores + b*4096);
  float4* dst = (float4*)(weights + b*4096);
  #pragma unroll
  for (int i = 0; i < 4; ++i){
    float4 v = src[tid + i*256];
    v.x = __builtin_amdgcn_exp2f((v.x - M) * LOG2E) * invd;
    v.y = __builtin_amdgcn_exp2f((v.y - M) * LOG2E) * invd;
    v.z = __builtin_amdgcn_exp2f((v.z - M) * LOG2E) * invd;
    v.w = __builtin_amdgcn_exp2f((v.w - M) * LOG2E) * invd;
    dst[tid + i*256] = v;
  }
}

// ---- K5: r_t = [c_t,h,x]·Wr^T + br; maxout pairs -> output [32][512]
__global__ __launch_bounds__(256) void final_kernel(
    const float* __restrict__ ct, const float* __restrict__ hvec,
    const float* __restrict__ x, const float* __restrict__ Wr,
    const float* __restrict__ br, float* __restrict__ out){
  __shared__ float xs[8][1536];
  int bt = blockIdx.x >> 4;
  int it = blockIdx.x & 15;
  int tid = threadIdx.x;
  int b0 = bt * 8;
  for (int idx = tid; idx < 8*1536; idx += 256){
    int bl = idx / 1536, j = idx % 1536;
    int b = b0 + bl;
    float v = (j < 512) ? ct[b*512 + j]
            : (j < 1024) ? hvec[b*512 + (j - 512)]
            : x[b*512 + (j - 1024)];
    xs[bl][j] = v;
  }
  __syncthreads();
  int i = it*64 + (tid & 63);
  int bl0 = (tid >> 6) * 2;
  const float4* wrow = (const float4*)(Wr + (size_t)i*1536);
  const float4* x0 = (const float4*)xs[bl0];
  const float4* x1 = (const float4*)xs[bl0 + 1];
  float a0 = 0.f, a1 = 0.f;
  #pragma unroll 4
  for (int k = 0; k < 384; ++k){
    float4 w = wrow[k];
    float4 u0 = x0[k], u1 = x1[k];
    a0 += w.x*u0.x + w.y*u0.y + w.z*u0.z + w.w*u0.w;
    a1 += w.x*u1.x + w.y*u1.y + w.z*u1.z + w.w*u1.w;
  }
  float bias = br[i];
  a0 += bias; a1 += bias;
  float n0 = __shfl_xor(a0, 1);
  float n1 = __shfl_xor(a1, 1);
  if ((tid & 1) == 0){
    out[(b0 + bl0    )*512 + (i >> 1)] = fmaxf(a0, n0);
    out[(b0 + bl0 + 1)*512 + (i >> 1)] = fmaxf(a1, n1);
  }
}

extern "C" void kernel_launch(void* const* d_in, const int* in_sizes, int n_in,
                              void* d_out, int out_size, void* d_ws, size_t ws_size,
                              hipStream_t stream){
  const float* ctx  = (const float*)d_in[0];
  const float* hvec = (const float*)d_in[1];
  const float* x    = (const float*)d_in[2];
  const float* We   = (const float*)d_in[3];
  const float* be   = (const float*)d_in[4];
  const float* Wd   = (const float*)d_in[5];
  const float* bd   = (const float*)d_in[6];
  const float* Wv   = (const float*)d_in[7];
  // d_in[8] = bv: dropped (softmax shift-invariance)
  const float* Wr   = (const float*)d_in[9];
  const float* br   = (const float*)d_in[10];

  float* out     = (float*)d_out;        // output [32][512]
  float* weights = out + 32*512;         // weights [32][4096]

  char* ws = (char*)d_ws;
  char* weFrag   = ws;                                   // 512 KiB
  float* scores  = (float*)(ws + (512 << 10));           // 512 KiB
  float* ctp     = (float*)(ws + (1024 << 10));          // 1 MiB (512x512 f32)
  float* MS      = (float*)(ws + (3 << 20));             // 4 KiB
  float* mbuf    = (float*)(ws + (3 << 20) + (16 << 10)); // 256 B
  float* ct      = (float*)(ws + (3 << 20) + (32 << 10)); // 64 KiB
  float* gd      = (float*)(ws + (3 << 20) + (96 << 10)); // 64 KiB region

  we_conv<<<128, 256, 0, stream>>>(We, (uint4*)weFrag);
  gd_kernel<<<128, 256, 0, stream>>>(hvec, Wd, bd, be, gd);
  score_kernel<<<256, 512, 0, stream>>>(ctx, (const uint4*)weFrag, gd, Wv,
                                        scores, ctp, MS);
  combine_kernel<<<32, 256, 0, stream>>>(ctp, MS, ct, mbuf);
  weights_kernel<<<32, 256, 0, stream>>>(scores, mbuf, weights);
  final_kernel<<<64, 256, 0, stream>>>(ct, hvec, x, Wr, br, out);
}

// Round 12
// 204.206 us; speedup vs baseline: 2.0606x; 1.0869x over previous
//
#include <hip/hip_runtime.h>

// Problem constants: B=32, S=4096, H=512, E=512
typedef __attribute__((ext_vector_type(8))) short bf16x8;
typedef __attribute__((ext_vector_type(16))) float f32x16;

typedef __attribute__((address_space(3))) unsigned int lds_u32;
typedef __attribute__((address_space(1))) unsigned int glb_u32;

union frag_u { bf16x8 v; unsigned int u[4]; };

__device__ inline unsigned int cvt_pk_bf16(float lo, float hi){
  unsigned int r;
  asm("v_cvt_pk_bf16_f32 %0, %1, %2" : "=v"(r) : "v"(lo), "v"(hi));
  return r;
}
__device__ inline bf16x8 pack8(float4 a, float4 b){
  union { unsigned int u[4]; bf16x8 v; } r;
  r.u[0]=cvt_pk_bf16(a.x,a.y); r.u[1]=cvt_pk_bf16(a.z,a.w);
  r.u[2]=cvt_pk_bf16(b.x,b.y); r.u[3]=cvt_pk_bf16(b.z,b.w);
  return r.v;
}
__device__ inline float fast_tanh(float x){
  float e = __builtin_amdgcn_exp2f(x * 2.8853900817779268f);
  return 1.0f - 2.0f * __builtin_amdgcn_rcpf(e + 1.0f);
}
#define PIN8(F) asm volatile("" : "+v"((F).u[0]), "+v"((F).u[1]), \
                                  "+v"((F).u[2]), "+v"((F).u[3]))
#define LOG2E 1.4426950408889634f

// ---- K0: We [512][512] f32 -> bf16 fragment images for mfma_32x32x16.
// Record (nc,t,lane), 16B: col = nc*32+(lane&31), k = t*16+(lane>>5)*8+j.
__global__ __launch_bounds__(256) void we_conv(const float* __restrict__ We,
                                               uint4* __restrict__ weFrag){
  int gid = blockIdx.x * 256 + threadIdx.x;   // 32768 = 16 nc x 32 t x 64 lanes
  int l  = gid & 63;
  int nc = gid >> 11;
  int t  = (gid >> 6) & 31;
  int colv = nc*32 + (l & 31);
  int k = t*16 + (l >> 5)*8;
  const float4* src = (const float4*)(We + colv*512 + k);
  float4 f0 = src[0], f1 = src[1];
  weFrag[gid] = make_uint4(cvt_pk_bf16(f0.x,f0.y), cvt_pk_bf16(f0.z,f0.w),
                           cvt_pk_bf16(f1.x,f1.y), cvt_pk_bf16(f1.z,f1.w));
}

// ---- K1: gd[b][k] = h[b,:]·Wd[k,:] + bd[k] + be[k]
__global__ __launch_bounds__(256) void gd_kernel(const float* __restrict__ hvec,
                                                 const float* __restrict__ Wd,
                                                 const float* __restrict__ bd,
                                                 const float* __restrict__ be,
                                                 float* __restrict__ gd){
  __shared__ float hs[512];
  int b = blockIdx.x >> 2, kc = blockIdx.x & 3;
  int tid = threadIdx.x;
  hs[tid]       = hvec[b*512 + tid];
  hs[tid + 256] = hvec[b*512 + 256 + tid];
  __syncthreads();
  int k  = kc*128 + (tid >> 1);
  int hh = (tid & 1) * 256;
  const float4* wrow = (const float4*)(Wd + (size_t)k*512 + hh);
  const float4* hv4  = (const float4*)(hs + hh);
  float acc = 0.f;
  #pragma unroll 8
  for (int i = 0; i < 64; ++i){
    float4 w = wrow[i]; float4 u = hv4[i];
    acc += w.x*u.x + w.y*u.y + w.z*u.z + w.w*u.w;
  }
  acc += __shfl_xor(acc, 1);
  if ((tid & 1) == 0) gd[b*512 + k] = acc + bd[k] + be[k];
}

// ---- K2: fused scores + flash partial context. r9 skeleton; inner phase
// rebuilt: FOUR independent 8-deep MFMA chains, plain ds_read->MFMA (no B
// pinning, no copy pipeline) -- compiler schedules lgkmcnt fine-grained.
__global__ __launch_bounds__(256, 2) void score_kernel(
    const float* __restrict__ ctx, const uint4* __restrict__ weFrag,
    const float* __restrict__ gd, const float* __restrict__ Wv,
    float* __restrict__ scores, float* __restrict__ ctp,
    float* __restrict__ MS){
  __shared__ char lds[2*32768 + 4096];       // 68 KiB: B dbuf + gdwv
  __shared__ float sc_lds[128];
  __shared__ float w_lds[128];
  __shared__ float red2[2];
  char* ldsB = lds;
  float* gdwv = (float*)(lds + 65536);       // [512 gd][512 Wv]

  const int tid  = threadIdx.x;
  const int wid  = tid >> 6;
  const int lane = tid & 63;
  const int bid  = blockIdx.x;
  const int row0 = bid * 128;
  const int b    = bid >> 5;                 // 32 blocks per batch row
  const int col  = lane & 31;
  const int hi   = lane >> 5;
  const int st   = bid & 15;                 // staggered start chunk

  #define ISSUE(NC, BUF) do { \
    const char* _g = (const char*)weFrag + (size_t)(NC)*32768 + wid*8192 + lane*16; \
    char* _l = ldsB + (BUF)*32768 + wid*8192; \
    _Pragma("unroll") \
    for (int _i = 0; _i < 8; ++_i) \
      __builtin_amdgcn_global_load_lds((const glb_u32*)(_g + _i*1024), \
                                       (lds_u32*)(_l + _i*1024), 16, 0, 0); \
  } while(0)

  ISSUE(st, 0);                              // first chunk in flight ASAP

  if (tid < 128) ((float4*)gdwv)[tid] = ((const float4*)(gd + b*512))[tid];
  else           ((float4*)gdwv)[tid] = ((const float4*)Wv)[tid - 128];

  // A-fragments: 32 k-steps, register/AGPR-resident, pinned once.
  frag_u afrag[32];
  {
    const float4* ap = (const float4*)(ctx + (size_t)(row0 + wid*32 + col)*512 + hi*8);
    #pragma unroll
    for (int t = 0; t < 32; ++t){
      afrag[t].v = pack8(ap[t*4], ap[t*4 + 1]);
      PIN8(afrag[t]);
    }
  }

  asm volatile("s_waitcnt lgkmcnt(0)" ::: "memory");  // gdwv ds_writes done

  float sc[16];
  #pragma unroll
  for (int r = 0; r < 16; ++r) sc[r] = 0.f;

  for (int nc = 0; nc < 16; ++nc){
    const int cur = (st + nc) & 15;          // chunk id this phase
    asm volatile("s_waitcnt vmcnt(0)" ::: "memory");
    __builtin_amdgcn_s_barrier();
    if (nc < 15) ISSUE((cur + 1) & 15, (nc + 1) & 1);

    const char* bb = ldsB + (nc & 1)*32768 + lane*16;
    f32x16 a0v, a1v, a2v, a3v;               // 4 independent chains
    #pragma unroll
    for (int r = 0; r < 16; ++r){ a0v[r]=0.f; a1v[r]=0.f; a2v[r]=0.f; a3v[r]=0.f; }

    __builtin_amdgcn_s_setprio(1);
    #pragma unroll
    for (int t = 0; t < 8; ++t){
      bf16x8 b0 = *(const bf16x8*)(bb + (t     )*1024);
      bf16x8 b1 = *(const bf16x8*)(bb + (t +  8)*1024);
      bf16x8 b2 = *(const bf16x8*)(bb + (t + 16)*1024);
      bf16x8 b3 = *(const bf16x8*)(bb + (t + 24)*1024);
      a0v = __builtin_amdgcn_mfma_f32_32x32x16_bf16(afrag[t     ].v, b0, a0v, 0, 0, 0);
      a1v = __builtin_amdgcn_mfma_f32_32x32x16_bf16(afrag[t +  8].v, b1, a1v, 0, 0, 0);
      a2v = __builtin_amdgcn_mfma_f32_32x32x16_bf16(afrag[t + 16].v, b2, a2v, 0, 0, 0);
      a3v = __builtin_amdgcn_mfma_f32_32x32x16_bf16(afrag[t + 24].v, b3, a3v, 0, 0, 0);
    }
    __builtin_amdgcn_s_setprio(0);

    float gdv = gdwv[cur*32 + col];
    float wvv = gdwv[512 + cur*32 + col];
    #pragma unroll
    for (int r = 0; r < 16; ++r)
      sc[r] += fast_tanh(((a0v[r] + a1v[r]) + (a2v[r] + a3v[r])) + gdv) * wvv;
  }
  #undef ISSUE

  // reduce over the 32 output columns
  #pragma unroll
  for (int r = 0; r < 16; ++r){
    #pragma unroll
    for (int m = 1; m <= 16; m <<= 1) sc[r] += __shfl_xor(sc[r], m);
  }
  if (col == 0){
    float* so = scores + row0 + wid*32 + 4*hi;
    #pragma unroll
    for (int r = 0; r < 16; ++r){
      int rr = (r & 3) + 8*(r >> 2);
      so[rr] = sc[r];                         // global (for weights kernel)
      sc_lds[wid*32 + 4*hi + rr] = sc[r];     // block-local
    }
  }
  __syncthreads();                            // sc_lds ready; ldsB reads done

  // ---- block-local softmax partials
  float M = -1e30f;
  {
    const float4* s4 = (const float4*)sc_lds;
    #pragma unroll
    for (int i = 0; i < 32; ++i){
      float4 v = s4[i];
      M = fmaxf(M, fmaxf(fmaxf(v.x, v.y), fmaxf(v.z, v.w)));
    }
  }
  if (tid < 128){
    float w = __builtin_amdgcn_exp2f((sc_lds[tid] - M) * LOG2E);
    w_lds[tid] = w;
    #pragma unroll
    for (int o = 1; o < 64; o <<= 1) w += __shfl_xor(w, o);
    if ((tid & 63) == 0) red2[tid >> 6] = w;
  }
  __syncthreads();
  float S_blk = red2[0] + red2[1];

  // ---- ctp[h] = sum_r w_r * A[r,h], two 64-row passes through ldsB
  float ctpA = 0.f, ctpB = 0.f;               // h = 2*tid, 2*tid+1
  #pragma unroll
  for (int p = 0; p < 2; ++p){
    if ((wid >> 1) == p){                     // waves 2p,2p+1 own these rows
      int rl = (wid & 1)*32 + col;            // local row 0..63
      char* dst = ldsB + rl*1024;
      int swz = (rl & 7) << 4;
      #pragma unroll
      for (int t = 0; t < 32; ++t)
        *(uint4*)(dst + ((t*32 + hi*16) ^ swz)) = *(uint4*)&afrag[t].u[0];
    }
    __syncthreads();
    const float* wp = w_lds + p*64;
    #pragma unroll 8
    for (int r = 0; r < 64; ++r){
      unsigned int u = *(const unsigned int*)(ldsB + r*1024 + ((tid*4) ^ ((r & 7) << 4)));
      float cw = wp[r];
      union { unsigned int q; float f; } flo, fhi;
      flo.q = u << 16;
      fhi.q = u & 0xffff0000u;
      ctpA += cw * flo.f;
      ctpB += cw * fhi.f;
    }
    __syncthreads();
  }
  ((float2*)(ctp + (size_t)bid*512))[tid] = make_float2(ctpA, ctpB);
  if (tid == 0){ MS[2*bid] = M; MS[2*bid + 1] = S_blk; }
}

// ---- K3: combine 32 chunk-partials per batch -> ct[b][512], mbuf[b]={M,1/den}
__global__ __launch_bounds__(256) void combine_kernel(const float* __restrict__ ctp,
                                                      const float* __restrict__ MS,
                                                      float* __restrict__ ct,
                                                      float* __restrict__ mbuf){
  __shared__ float wsh[32];
  __shared__ float msh[2];
  int b = blockIdx.x, tid = threadIdx.x;
  if (tid < 64){
    int i = tid & 31;
    float Mi = MS[(b*32 + i)*2];
    float Si = MS[(b*32 + i)*2 + 1];
    float M = Mi;
    #pragma unroll
    for (int o = 1; o < 32; o <<= 1) M = fmaxf(M, __shfl_xor(M, o));
    float w = __builtin_amdgcn_exp2f((Mi - M) * LOG2E);
    float d = w * Si;
    #pragma unroll
    for (int o = 1; o < 32; o <<= 1) d += __shfl_xor(d, o);
    if (tid < 32) wsh[i] = w;
    if (tid == 0){ msh[0] = M; msh[1] = 1.0f / d; }
  }
  __syncthreads();
  float invd = msh[1];
  float a0 = 0.f, a1 = 0.f;
  #pragma unroll
  for (int i = 0; i < 32; ++i){
    float2 v = ((const float2*)(ctp + (size_t)(b*32 + i)*512))[tid];
    float w = wsh[i];
    a0 += w * v.x; a1 += w * v.y;
  }
  ((float2*)(ct + b*512))[tid] = make_float2(a0 * invd, a1 * invd);
  if (tid == 0){ mbuf[2*b] = msh[0]; mbuf[2*b + 1] = invd; }
}

// ---- K4: weights[b][s] = exp(score - M_b) * inv_denom
__global__ __launch_bounds__(256) void weights_kernel(const float* __restrict__ scores,
                                                      const float* __restrict__ mbuf,
                                                      float* __restrict__ weights){
  int b = blockIdx.x, tid = threadIdx.x;
  float M = mbuf[2*b], invd = mbuf[2*b + 1];
  const float4* src = (const float4*)(scores + b*4096);
  float4* dst = (float4*)(weights + b*4096);
  #pragma unroll
  for (int i = 0; i < 4; ++i){
    float4 v = src[tid + i*256];
    v.x = __builtin_amdgcn_exp2f((v.x - M) * LOG2E) * invd;
    v.y = __builtin_amdgcn_exp2f((v.y - M) * LOG2E) * invd;
    v.z = __builtin_amdgcn_exp2f((v.z - M) * LOG2E) * invd;
    v.w = __builtin_amdgcn_exp2f((v.w - M) * LOG2E) * invd;
    dst[tid + i*256] = v;
  }
}

// ---- K5: r_t = [c_t,h,x]·Wr^T + br; maxout pairs -> output [32][512]
__global__ __launch_bounds__(256) void final_kernel(
    const float* __restrict__ ct, const float* __restrict__ hvec,
    const float* __restrict__ x, const float* __restrict__ Wr,
    const float* __restrict__ br, float* __restrict__ out){
  __shared__ float xs[8][1536];
  int bt = blockIdx.x >> 4;
  int it = blockIdx.x & 15;
  int tid = threadIdx.x;
  int b0 = bt * 8;
  for (int idx = tid; idx < 8*1536; idx += 256){
    int bl = idx / 1536, j = idx % 1536;
    int b = b0 + bl;
    float v = (j < 512) ? ct[b*512 + j]
            : (j < 1024) ? hvec[b*512 + (j - 512)]
            : x[b*512 + (j - 1024)];
    xs[bl][j] = v;
  }
  __syncthreads();
  int i = it*64 + (tid & 63);
  int bl0 = (tid >> 6) * 2;
  const float4* wrow = (const float4*)(Wr + (size_t)i*1536);
  const float4* x0 = (const float4*)xs[bl0];
  const float4* x1 = (const float4*)xs[bl0 + 1];
  float a0 = 0.f, a1 = 0.f;
  #pragma unroll 4
  for (int k = 0; k < 384; ++k){
    float4 w = wrow[k];
    float4 u0 = x0[k], u1 = x1[k];
    a0 += w.x*u0.x + w.y*u0.y + w.z*u0.z + w.w*u0.w;
    a1 += w.x*u1.x + w.y*u1.y + w.z*u1.z + w.w*u1.w;
  }
  float bias = br[i];
  a0 += bias; a1 += bias;
  float n0 = __shfl_xor(a0, 1);
  float n1 = __shfl_xor(a1, 1);
  if ((tid & 1) == 0){
    out[(b0 + bl0    )*512 + (i >> 1)] = fmaxf(a0, n0);
    out[(b0 + bl0 + 1)*512 + (i >> 1)] = fmaxf(a1, n1);
  }
}

extern "C" void kernel_launch(void* const* d_in, const int* in_sizes, int n_in,
                              void* d_out, int out_size, void* d_ws, size_t ws_size,
                              hipStream_t stream){
  const float* ctx  = (const float*)d_in[0];
  const float* hvec = (const float*)d_in[1];
  const float* x    = (const float*)d_in[2];
  const float* We   = (const float*)d_in[3];
  const float* be   = (const float*)d_in[4];
  const float* Wd   = (const float*)d_in[5];
  const float* bd   = (const float*)d_in[6];
  const float* Wv   = (const float*)d_in[7];
  // d_in[8] = bv: dropped (softmax shift-invariance)
  const float* Wr   = (const float*)d_in[9];
  const float* br   = (const float*)d_in[10];

  float* out     = (float*)d_out;        // output [32][512]
  float* weights = out + 32*512;         // weights [32][4096]

  char* ws = (char*)d_ws;
  char* weFrag   = ws;                                   // 512 KiB
  float* scores  = (float*)(ws + (512 << 10));           // 512 KiB
  float* ctp     = (float*)(ws + (1024 << 10));          // 2 MiB (1024x512 f32)
  float* MS      = (float*)(ws + (3 << 20));             // 8 KiB
  float* mbuf    = (float*)(ws + (3 << 20) + (16 << 10)); // 256 B
  float* ct      = (float*)(ws + (3 << 20) + (32 << 10)); // 64 KiB
  float* gd      = (float*)(ws + (3 << 20) + (96 << 10)); // 64 KiB region

  we_conv<<<128, 256, 0, stream>>>(We, (uint4*)weFrag);
  gd_kernel<<<128, 256, 0, stream>>>(hvec, Wd, bd, be, gd);
  score_kernel<<<1024, 256, 0, stream>>>(ctx, (const uint4*)weFrag, gd, Wv,
                                         scores, ctp, MS);
  combine_kernel<<<32, 256, 0, stream>>>(ctp, MS, ct, mbuf);
  weights_kernel<<<32, 256, 0, stream>>>(scores, mbuf, weights);
  final_kernel<<<64, 256, 0, stream>>>(ct, hvec, x, Wr, br, out);
}